// Round 4
// baseline (172.698 us; speedup 1.0000x reference)
//
#include <hip/hip_runtime.h>
#include <hip/hip_bf16.h>
#include <cstddef>

// Dims fixed by reference: B=2, S=2048, H=1024, NH=4, DH=256
constexpr int Bx = 2, Sx = 2048, Hx = 1024, NHx = 4, DHx = 256;
constexpr float RSQ = 0.0625f;   // 1/sqrt(256)

typedef __attribute__((ext_vector_type(8))) short    bf16x8;
typedef __attribute__((ext_vector_type(4))) float    f32x4;

__device__ __forceinline__ float logsigf(float x) {
  return (x >= 0.0f) ? -log1pf(expf(-x)) : x - log1pf(expf(x));
}
__device__ __forceinline__ unsigned short f2bf(float x) {  // RNE f32->bf16
  unsigned u = __builtin_bit_cast(unsigned, x);
  u = (u + 0x7fffu + ((u >> 16) & 1u)) >> 16;
  return (unsigned short)u;
}
__device__ __forceinline__ unsigned pk2bf(float a, float b) {
  return (unsigned)f2bf(a) | ((unsigned)f2bf(b) << 16);
}

// ---------- K1: gates (ig/fg) + bf16 side-copies of Q,K ---------------------
__global__ __launch_bounds__(256)
void gates_kernel(const float* __restrict__ q, const float* __restrict__ k,
                  const float* __restrict__ v,
                  const float* __restrict__ wi, const float* __restrict__ bi,
                  const float* __restrict__ wf, const float* __restrict__ bf,
                  float* __restrict__ ig, float* __restrict__ fg,
                  unsigned short* __restrict__ Qb, unsigned short* __restrict__ Kb)
{
  const int bs = blockIdx.x;           // b*S + s
  const int t  = threadIdx.x;
  const int b = bs >> 11, spos = bs & 2047;
  float p[8] = {0,0,0,0,0,0,0,0};
  const size_t rowoff = (size_t)bs * Hx;
  for (int idx = t; idx < 3 * Hx; idx += 256) {
    float gv;
    if (idx < Hx) {
      gv = q[rowoff + idx];
      Qb[((size_t)(b * NHx + (idx >> 8)) * Sx + spos) * DHx + (idx & 255)] = f2bf(gv);
    } else if (idx < 2 * Hx) {
      gv = k[rowoff + idx - Hx];
      int kd = idx - Hx;
      Kb[((size_t)(b * NHx + (kd >> 8)) * Sx + spos) * DHx + (kd & 255)] = f2bf(gv);
    } else {
      gv = v[rowoff + idx - 2 * Hx];
    }
#pragma unroll
    for (int h = 0; h < NHx; ++h) {
      p[h]     += gv * wi[h * 3 * Hx + idx];
      p[4 + h] += gv * wf[h * 3 * Hx + idx];
    }
  }
  __shared__ float red[8][256];
#pragma unroll
  for (int g2 = 0; g2 < 8; ++g2) red[g2][t] = p[g2];
  __syncthreads();
  for (int s2 = 128; s2 > 0; s2 >>= 1) {
    if (t < s2) {
#pragma unroll
      for (int g2 = 0; g2 < 8; ++g2) red[g2][t] += red[g2][t + s2];
    }
    __syncthreads();
  }
  if (t < 8) {
    const int h = t & 3;
    const size_t o = ((size_t)(b * NHx + h)) * Sx + spos;
    if (t < 4) ig[o] = red[t][0] + bi[h];
    else       fg[o] = red[t][0] + bf[h];
  }
}

// ---------- K2: per-(b,h) scan: a[], M[], exp(-m)[] -------------------------
__global__ __launch_bounds__(256)
void scan_kernel(const float* __restrict__ ig, const float* __restrict__ fg,
                 float* __restrict__ av, float* __restrict__ Mv,
                 float* __restrict__ nfv)
{
  const int bh = blockIdx.x;
  const int t  = threadIdx.x;
  const size_t base = (size_t)bh * Sx;
  const int s0 = t * 8;
  float4 f0 = *(const float4*)(fg + base + s0);
  float4 f1 = *(const float4*)(fg + base + s0 + 4);
  float4 g0 = *(const float4*)(ig + base + s0);
  float4 g1 = *(const float4*)(ig + base + s0 + 4);
  float xf[8] = {f0.x,f0.y,f0.z,f0.w,f1.x,f1.y,f1.z,f1.w};
  float xi[8] = {g0.x,g0.y,g0.z,g0.w,g1.x,g1.y,g1.z,g1.w};
  float ps[8];
  float run = 0.0f;
#pragma unroll
  for (int i = 0; i < 8; ++i) { run += logsigf(xf[i]); ps[i] = run; }
  __shared__ float ssum[256];
  __shared__ float smax[256];
  ssum[t] = run;
  __syncthreads();
  for (int st = 1; st < 256; st <<= 1) {
    float addv = (t >= st) ? ssum[t - st] : 0.0f;
    __syncthreads();
    ssum[t] += addv;
    __syncthreads();
  }
  const float exs = (t > 0) ? ssum[t - 1] : 0.0f;
  float a[8], pm[8];
  float rm = -INFINITY;
#pragma unroll
  for (int i = 0; i < 8; ++i) {
    a[i] = xi[i] - (exs + ps[i]);
    rm = fmaxf(rm, a[i]);
    pm[i] = rm;
  }
  smax[t] = rm;
  __syncthreads();
  for (int st = 1; st < 256; st <<= 1) {
    float mv = (t >= st) ? smax[t - st] : -INFINITY;
    __syncthreads();
    smax[t] = fmaxf(smax[t], mv);
    __syncthreads();
  }
  const float exm = (t > 0) ? smax[t - 1] : -INFINITY;
#pragma unroll
  for (int i = 0; i < 8; ++i) {
    const float M = fmaxf(exm, pm[i]);
    const float F = exs + ps[i];
    av[base + s0 + i]  = a[i];
    Mv[base + s0 + i]  = M;
    nfv[base + s0 + i] = expf(-(F + M));
  }
}

// ---------- K3: V -> bf16 transposed global Vt[bh][d][s] --------------------
__global__ __launch_bounds__(256)
void vtrans_kernel(const float* __restrict__ v, unsigned short* __restrict__ vt)
{
  __shared__ float tile[64][68];
  const int st0 = blockIdx.x * 64, dt0 = blockIdx.y * 64;
  const int bh = blockIdx.z, b = bh >> 2, h = bh & 3;
  const int t = threadIdx.x;
#pragma unroll
  for (int i = 0; i < 4; ++i) {
    int u = t + 256 * i;
    int r = u >> 4, c4 = (u & 15) * 4;
    const float* p = v + ((size_t)(b * Sx) + st0 + r) * Hx + h * DHx + dt0 + c4;
    float4 vv = *(const float4*)p;
    tile[r][c4] = vv.x; tile[r][c4+1] = vv.y; tile[r][c4+2] = vv.z; tile[r][c4+3] = vv.w;
  }
  __syncthreads();
#pragma unroll
  for (int i = 0; i < 4; ++i) {
    int u = t + 256 * i;
    int dr = u >> 4, c4 = (u & 15) * 4;
    ushort4 o;
    o.x = f2bf(tile[c4+0][dr]); o.y = f2bf(tile[c4+1][dr]);
    o.z = f2bf(tile[c4+2][dr]); o.w = f2bf(tile[c4+3][dr]);
    *(ushort4*)(vt + ((size_t)bh * DHx + dt0 + dr) * Sx + st0 + c4) = o;
  }
}

// ---------- K4: flash mLSTM on MFMA, BQ=32, 4 waves, direct-L2 frags ---------
// 256 thr = 4 waves. Block: 32 q-rows (tile ti), key tiles of 64.
// QK: wave ks handles 16-key slice x 32 q (2 q-groups), Q in regs.
// P via LDS (double-buffered). PV: wave ds handles 64-dim slice x 32 q.
// Epilogue fully in registers + 1.5KB LDS cross-wave exchange.
__global__ __launch_bounds__(256, 3)
void mlstm_mfma(const unsigned short* __restrict__ Qb,
                const unsigned short* __restrict__ Kb,
                const unsigned short* __restrict__ Vt,
                const float* __restrict__ av, const float* __restrict__ Mv,
                const float* __restrict__ nfv, const float* __restrict__ lnw,
                float* __restrict__ out)
{
  __shared__ __align__(16) unsigned short Pls[2][32][72];  // 9.2 KB
  __shared__ float red[4][2][16][3];                       // 1.5 KB

  const int bh = blockIdx.x, b = bh >> 2, h = bh & 3;
  const int ti = (int)gridDim.y - 1 - (int)blockIdx.y;   // big tiles first
  const int i0 = ti * 32;
  const int tid = threadIdx.x;
  const int w = tid >> 6, l = tid & 63;
  const int lg = l >> 4, ll = l & 15;
  const size_t bhS = (size_t)bh * Sx;

  // Q B-frags for 32 q-rows (2 groups of 16), M per q-group
  bf16x8 qf[2][8];
  float Mq[2];
#pragma unroll
  for (int qg = 0; qg < 2; ++qg) {
    const int qrow = i0 + qg * 16 + ll;
    const unsigned short* qp = Qb + (bhS + qrow) * DHx + lg * 8;
#pragma unroll
    for (int dstep = 0; dstep < 8; ++dstep)
      qf[qg][dstep] = *(const bf16x8*)(qp + dstep * 32);
    Mq[qg] = Mv[bhS + qrow];
  }

  f32x4 acc[4][2];   // [dt][qg]: O^T (d = w*64+dt*16+lg*4+r, q = qg*16+ll)
#pragma unroll
  for (int dt = 0; dt < 4; ++dt)
#pragma unroll
    for (int qg = 0; qg < 2; ++qg) acc[dt][qg] = f32x4{0, 0, 0, 0};
  float rsum[2] = {0.f, 0.f};

  const int nt = ti / 2 + 1;        // 64-key tiles covering [0, i0+32)
  for (int tj = 0; tj < nt; ++tj) {
    const int j0 = tj * 64;
    const int kb = j0 + w * 16;
    // ---- QK: K frags from L2, 16 MFMA ----
    f32x4 st0 = {0,0,0,0}, st1 = {0,0,0,0};
    {
      const unsigned short* kp = Kb + (bhS + kb + ll) * DHx + lg * 8;
#pragma unroll
      for (int dstep = 0; dstep < 8; ++dstep) {
        bf16x8 kf = *(const bf16x8*)(kp + dstep * 32);
        st0 = __builtin_amdgcn_mfma_f32_16x16x32_bf16(kf, qf[0][dstep], st0, 0, 0, 0);
        st1 = __builtin_amdgcn_mfma_f32_16x16x32_bf16(kf, qf[1][dstep], st1, 0, 0, 0);
      }
    }
    const f32x4 a4 = *(const f32x4*)(av + bhS + kb + lg * 4);
    // ---- transform + P write ----
#pragma unroll
    for (int qg = 0; qg < 2; ++qg) {
      const f32x4 s = qg ? st1 : st0;
      const int qrow = i0 + qg * 16 + ll;
      const int k0i = kb + lg * 4;
      float p0 = (k0i + 0 <= qrow) ? s[0] * (RSQ * __expf(a4[0] - Mq[qg])) : 0.f;
      float p1 = (k0i + 1 <= qrow) ? s[1] * (RSQ * __expf(a4[1] - Mq[qg])) : 0.f;
      float p2 = (k0i + 2 <= qrow) ? s[2] * (RSQ * __expf(a4[2] - Mq[qg])) : 0.f;
      float p3 = (k0i + 3 <= qrow) ? s[3] * (RSQ * __expf(a4[3] - Mq[qg])) : 0.f;
      rsum[qg] += (p0 + p1) + (p2 + p3);
      uint2 pk = make_uint2(pk2bf(p0, p1), pk2bf(p2, p3));
      *(uint2*)&Pls[tj & 1][qg * 16 + ll][w * 16 + lg * 4] = pk;
    }
    __syncthreads();
    // ---- PV: V frags from L2, P frags from LDS, 16 MFMA ----
    const unsigned short* vpb = Vt + ((size_t)bh * DHx + w * 64 + ll) * Sx + j0 + lg * 8;
#pragma unroll
    for (int kap = 0; kap < 2; ++kap) {
      bf16x8 pf[2];
#pragma unroll
      for (int qg = 0; qg < 2; ++qg)
        pf[qg] = *(const bf16x8*)&Pls[tj & 1][qg * 16 + ll][kap * 32 + lg * 8];
#pragma unroll
      for (int dt = 0; dt < 4; ++dt) {
        bf16x8 vf = *(const bf16x8*)(vpb + (size_t)dt * 16 * Sx + kap * 32);
#pragma unroll
        for (int qg = 0; qg < 2; ++qg)
          acc[dt][qg] = __builtin_amdgcn_mfma_f32_16x16x32_bf16(vf, pf[qg], acc[dt][qg], 0, 0, 0);
      }
    }
  }

  // ---- cross-wave reductions: rsum, s1, s2 per q-row ----
#pragma unroll
  for (int qg = 0; qg < 2; ++qg) {
    float rs = rsum[qg];
    float s1 = 0.f, s2 = 0.f;
#pragma unroll
    for (int dt = 0; dt < 4; ++dt)
#pragma unroll
      for (int r = 0; r < 4; ++r) {
        const float x = acc[dt][qg][r];
        s1 += x; s2 += x * x;
      }
    rs += __shfl_xor(rs, 16); rs += __shfl_xor(rs, 32);
    s1 += __shfl_xor(s1, 16); s1 += __shfl_xor(s1, 32);
    s2 += __shfl_xor(s2, 16); s2 += __shfl_xor(s2, 32);
    if (l < 16) {
      red[w][qg][l][0] = rs;
      red[w][qg][l][1] = s1;
      red[w][qg][l][2] = s2;
    }
  }
  __syncthreads();

  // ---- epilogue: normalizer + group-LN, direct from accumulators ----
#pragma unroll
  for (int qg = 0; qg < 2; ++qg) {
    const int qrow = i0 + qg * 16 + ll;
    float rs = 0.f, s1 = 0.f, s2 = 0.f;
#pragma unroll
    for (int wi2 = 0; wi2 < 4; ++wi2) {
      rs += red[wi2][qg][ll][0];
      s1 += red[wi2][qg][ll][1];
      s2 += red[wi2][qg][ll][2];
    }
    const float nf = nfv[bhS + qrow];
    const float inv = 1.f / (fmaxf(fabsf(rs), nf) + 1e-6f);
    const float mean = s1 * inv * (1.f / 256.f);
    const float ex2  = s2 * inv * inv * (1.f / 256.f);
    const float var  = ex2 - mean * mean;
    const float rstd = rsqrtf(var + 1e-5f);
    float* op = out + ((size_t)b * Sx + qrow) * Hx + h * DHx;
#pragma unroll
    for (int dt = 0; dt < 4; ++dt) {
      const int dbase = w * 64 + dt * 16 + lg * 4;
      f32x4 lw = *(const f32x4*)(lnw + h * DHx + dbase);
      float4 o;
      o.x = (acc[dt][qg][0] * inv - mean) * rstd * (1.f + lw[0]);
      o.y = (acc[dt][qg][1] * inv - mean) * rstd * (1.f + lw[1]);
      o.z = (acc[dt][qg][2] * inv - mean) * rstd * (1.f + lw[2]);
      o.w = (acc[dt][qg][3] * inv - mean) * rstd * (1.f + lw[3]);
      *(float4*)(op + dbase) = o;
    }
  }
}

extern "C" void kernel_launch(void* const* d_in, const int* in_sizes, int n_in,
                              void* d_out, int out_size, void* d_ws, size_t ws_size,
                              hipStream_t stream) {
  const float* q   = (const float*)d_in[0];
  const float* k   = (const float*)d_in[1];
  const float* v   = (const float*)d_in[2];
  const float* wi  = (const float*)d_in[3];
  const float* bi  = (const float*)d_in[4];
  const float* wf  = (const float*)d_in[5];
  const float* bf  = (const float*)d_in[6];
  const float* lnw = (const float*)d_in[7];
  float* out = (float*)d_out;
  float* ws  = (float*)d_ws;

  const int G = Bx * NHx * Sx;         // 16384
  float* ig  = ws;
  float* fg  = ws + (size_t)G;
  float* av  = ws + (size_t)2 * G;
  float* Mv  = ws + (size_t)3 * G;
  float* nfv = ws + (size_t)4 * G;
  unsigned short* Qb = (unsigned short*)(ws + (size_t)5 * G);
  unsigned short* Kb = Qb + (size_t)Bx * Sx * Hx;   // 4,194,304 elems
  unsigned short* Vt = Kb + (size_t)Bx * Sx * Hx;
  // total ws use: ~24.3 MB

  gates_kernel<<<Bx * Sx, 256, 0, stream>>>(q, k, v, wi, bi, wf, bf, ig, fg, Qb, Kb);
  scan_kernel<<<Bx * NHx, 256, 0, stream>>>(ig, fg, av, Mv, nfv);
  dim3 gT(Sx / 64, DHx / 64, Bx * NHx);
  vtrans_kernel<<<gT, 256, 0, stream>>>(v, Vt);
  dim3 g4(Bx * NHx, Sx / 32);          // x = bh (fastest), y = q-tile
  mlstm_mfma<<<g4, 256, 0, stream>>>(Qb, Kb, Vt, av, Mv, nfv, lnw, out);
}

// Round 5
// 134.683 us; speedup vs baseline: 1.2823x; 1.2823x over previous
//
#include <hip/hip_runtime.h>
#include <hip/hip_bf16.h>
#include <cstddef>

// Dims fixed by reference: B=2, S=2048, H=1024, NH=4, DH=256
constexpr int Bx = 2, Sx = 2048, Hx = 1024, NHx = 4, DHx = 256;
constexpr float RSQ = 0.0625f;   // 1/sqrt(256)

typedef __attribute__((ext_vector_type(8))) short    bf16x8;
typedef __attribute__((ext_vector_type(4))) float    f32x4;

__device__ __forceinline__ float logsigf(float x) {
  return (x >= 0.0f) ? -log1pf(expf(-x)) : x - log1pf(expf(x));
}
__device__ __forceinline__ unsigned short f2bf(float x) {  // RNE f32->bf16
  unsigned u = __builtin_bit_cast(unsigned, x);
  u = (u + 0x7fffu + ((u >> 16) & 1u)) >> 16;
  return (unsigned short)u;
}
__device__ __forceinline__ unsigned pk2bf(float a, float b) {
  return (unsigned)f2bf(a) | ((unsigned)f2bf(b) << 16);
}

// ---------- K1: gates (ig/fg) + bf16 side-copies of Q,K ---------------------
__global__ __launch_bounds__(256)
void gates_kernel(const float* __restrict__ q, const float* __restrict__ k,
                  const float* __restrict__ v,
                  const float* __restrict__ wi, const float* __restrict__ bi,
                  const float* __restrict__ wf, const float* __restrict__ bf,
                  float* __restrict__ ig, float* __restrict__ fg,
                  unsigned short* __restrict__ Qb, unsigned short* __restrict__ Kb)
{
  const int bs = blockIdx.x;           // b*S + s
  const int t  = threadIdx.x;
  const int b = bs >> 11, spos = bs & 2047;
  float p[8] = {0,0,0,0,0,0,0,0};
  const size_t rowoff = (size_t)bs * Hx;
  for (int idx = t; idx < 3 * Hx; idx += 256) {
    float gv;
    if (idx < Hx) {
      gv = q[rowoff + idx];
      Qb[((size_t)(b * NHx + (idx >> 8)) * Sx + spos) * DHx + (idx & 255)] = f2bf(gv);
    } else if (idx < 2 * Hx) {
      gv = k[rowoff + idx - Hx];
      int kd = idx - Hx;
      Kb[((size_t)(b * NHx + (kd >> 8)) * Sx + spos) * DHx + (kd & 255)] = f2bf(gv);
    } else {
      gv = v[rowoff + idx - 2 * Hx];
    }
#pragma unroll
    for (int h = 0; h < NHx; ++h) {
      p[h]     += gv * wi[h * 3 * Hx + idx];
      p[4 + h] += gv * wf[h * 3 * Hx + idx];
    }
  }
  __shared__ float red[8][256];
#pragma unroll
  for (int g2 = 0; g2 < 8; ++g2) red[g2][t] = p[g2];
  __syncthreads();
  for (int s2 = 128; s2 > 0; s2 >>= 1) {
    if (t < s2) {
#pragma unroll
      for (int g2 = 0; g2 < 8; ++g2) red[g2][t] += red[g2][t + s2];
    }
    __syncthreads();
  }
  if (t < 8) {
    const int h = t & 3;
    const size_t o = ((size_t)(b * NHx + h)) * Sx + spos;
    if (t < 4) ig[o] = red[t][0] + bi[h];
    else       fg[o] = red[t][0] + bf[h];
  }
}

// ---------- K2: per-(b,h) scan: a[], M[], exp(-m)[] -------------------------
__global__ __launch_bounds__(256)
void scan_kernel(const float* __restrict__ ig, const float* __restrict__ fg,
                 float* __restrict__ av, float* __restrict__ Mv,
                 float* __restrict__ nfv)
{
  const int bh = blockIdx.x;
  const int t  = threadIdx.x;
  const size_t base = (size_t)bh * Sx;
  const int s0 = t * 8;
  float4 f0 = *(const float4*)(fg + base + s0);
  float4 f1 = *(const float4*)(fg + base + s0 + 4);
  float4 g0 = *(const float4*)(ig + base + s0);
  float4 g1 = *(const float4*)(ig + base + s0 + 4);
  float xf[8] = {f0.x,f0.y,f0.z,f0.w,f1.x,f1.y,f1.z,f1.w};
  float xi[8] = {g0.x,g0.y,g0.z,g0.w,g1.x,g1.y,g1.z,g1.w};
  float ps[8];
  float run = 0.0f;
#pragma unroll
  for (int i = 0; i < 8; ++i) { run += logsigf(xf[i]); ps[i] = run; }
  __shared__ float ssum[256];
  __shared__ float smax[256];
  ssum[t] = run;
  __syncthreads();
  for (int st = 1; st < 256; st <<= 1) {
    float addv = (t >= st) ? ssum[t - st] : 0.0f;
    __syncthreads();
    ssum[t] += addv;
    __syncthreads();
  }
  const float exs = (t > 0) ? ssum[t - 1] : 0.0f;
  float a[8], pm[8];
  float rm = -INFINITY;
#pragma unroll
  for (int i = 0; i < 8; ++i) {
    a[i] = xi[i] - (exs + ps[i]);
    rm = fmaxf(rm, a[i]);
    pm[i] = rm;
  }
  smax[t] = rm;
  __syncthreads();
  for (int st = 1; st < 256; st <<= 1) {
    float mv = (t >= st) ? smax[t - st] : -INFINITY;
    __syncthreads();
    smax[t] = fmaxf(smax[t], mv);
    __syncthreads();
  }
  const float exm = (t > 0) ? smax[t - 1] : -INFINITY;
#pragma unroll
  for (int i = 0; i < 8; ++i) {
    const float M = fmaxf(exm, pm[i]);
    const float F = exs + ps[i];
    av[base + s0 + i]  = a[i];
    Mv[base + s0 + i]  = M;
    nfv[base + s0 + i] = expf(-(F + M));
  }
}

// ---------- K3: V -> bf16 transposed global Vt[bh][d][s] --------------------
__global__ __launch_bounds__(256)
void vtrans_kernel(const float* __restrict__ v, unsigned short* __restrict__ vt)
{
  __shared__ float tile[64][68];
  const int st0 = blockIdx.x * 64, dt0 = blockIdx.y * 64;
  const int bh = blockIdx.z, b = bh >> 2, h = bh & 3;
  const int t = threadIdx.x;
#pragma unroll
  for (int i = 0; i < 4; ++i) {
    int u = t + 256 * i;
    int r = u >> 4, c4 = (u & 15) * 4;
    const float* p = v + ((size_t)(b * Sx) + st0 + r) * Hx + h * DHx + dt0 + c4;
    float4 vv = *(const float4*)p;
    tile[r][c4] = vv.x; tile[r][c4+1] = vv.y; tile[r][c4+2] = vv.z; tile[r][c4+3] = vv.w;
  }
  __syncthreads();
#pragma unroll
  for (int i = 0; i < 4; ++i) {
    int u = t + 256 * i;
    int dr = u >> 4, c4 = (u & 15) * 4;
    ushort4 o;
    o.x = f2bf(tile[c4+0][dr]); o.y = f2bf(tile[c4+1][dr]);
    o.z = f2bf(tile[c4+2][dr]); o.w = f2bf(tile[c4+3][dr]);
    *(ushort4*)(vt + ((size_t)bh * DHx + dt0 + dr) * Sx + st0 + c4) = o;
  }
}

// ---------- K4: flash mLSTM on MFMA -----------------------------------------
// 512 thr = 8 waves. BQ=32 q-rows per block, BK=128 keys per iter.
// QK: wave w: keys [w*16, w*16+16) x 32 q; Q frags from LDS, K frags from L2.
// PV: wave w: d-slice [w*32, w*32+32) x 32 q; V frags from L2, P from LDS.
// One barrier/iter, P double-buffered. Epilogue in regs + small LDS exchange.
constexpr int QSTR = 264;   // Qls row stride (bf16 elems)
constexpr int PSTR = 136;   // Pls row stride

__global__ __launch_bounds__(512, 4)
void mlstm_mfma(const unsigned short* __restrict__ Qb,
                const unsigned short* __restrict__ Kb,
                const unsigned short* __restrict__ Vt,
                const float* __restrict__ av, const float* __restrict__ Mv,
                const float* __restrict__ nfv, const float* __restrict__ lnw,
                float* __restrict__ out)
{
  __shared__ __align__(16) unsigned short Qls[32 * QSTR];     // 16.9 KB
  __shared__ __align__(16) unsigned short Pls[2][32 * PSTR];  // 17.4 KB
  __shared__ float red[8][2][16][3];                          // 3 KB

  const int bh = blockIdx.x, b = bh >> 2, h = bh & 3;
  const int ti = (int)gridDim.y - 1 - (int)blockIdx.y;   // big tiles first
  const int i0 = ti * 32;
  const int tid = threadIdx.x;
  const int w = tid >> 6, l = tid & 63;
  const int lg = l >> 4, ll = l & 15;
  const size_t bhS = (size_t)bh * Sx;

  // stage Q tile (32 x 256) into LDS once
  {
    const int r = tid >> 4, c = (tid & 15) * 16;
    const unsigned short* qp = Qb + (bhS + i0 + r) * DHx + c;
    bf16x8 v0 = *(const bf16x8*)qp;
    bf16x8 v1 = *(const bf16x8*)(qp + 8);
    *(bf16x8*)&Qls[r * QSTR + c] = v0;
    *(bf16x8*)&Qls[r * QSTR + c + 8] = v1;
  }
  float Mq[2], nfq[2];
#pragma unroll
  for (int qg = 0; qg < 2; ++qg) {
    Mq[qg]  = Mv[bhS + i0 + qg * 16 + ll];
    nfq[qg] = nfv[bhS + i0 + qg * 16 + ll];
  }
  f32x4 acc[2][2];   // [dt][qg]: d = w*32+dt*16+lg*4+r, q = qg*16+ll
#pragma unroll
  for (int dt = 0; dt < 2; ++dt)
#pragma unroll
    for (int qg = 0; qg < 2; ++qg) acc[dt][qg] = f32x4{0, 0, 0, 0};
  float rsum[2] = {0.f, 0.f};
  __syncthreads();

  const int nt = (i0 + 32 + 127) >> 7;
  for (int tj = 0; tj < nt; ++tj) {
    const int j0 = tj << 7;
    const int kb = j0 + w * 16;
    // ---- K frags from L2 (issued first, hidden under LDS reads) ----
    bf16x8 kf[8];
    {
      const unsigned short* kp = Kb + (bhS + kb + ll) * DHx + lg * 8;
#pragma unroll
      for (int d8 = 0; d8 < 8; ++d8) kf[d8] = *(const bf16x8*)(kp + d8 * 32);
    }
    const f32x4 a4 = *(const f32x4*)(av + bhS + kb + lg * 4);
    // ---- QK: Q frags from LDS, 16 MFMA ----
    f32x4 st0 = {0,0,0,0}, st1 = {0,0,0,0};
#pragma unroll
    for (int d8 = 0; d8 < 8; ++d8) {
      bf16x8 q0 = *(const bf16x8*)&Qls[ll * QSTR + d8 * 32 + lg * 8];
      bf16x8 q1 = *(const bf16x8*)&Qls[(16 + ll) * QSTR + d8 * 32 + lg * 8];
      st0 = __builtin_amdgcn_mfma_f32_16x16x32_bf16(kf[d8], q0, st0, 0, 0, 0);
      st1 = __builtin_amdgcn_mfma_f32_16x16x32_bf16(kf[d8], q1, st1, 0, 0, 0);
    }
    // ---- transform + P write ----
#pragma unroll
    for (int qg = 0; qg < 2; ++qg) {
      const f32x4 s = qg ? st1 : st0;
      const int qrow = i0 + qg * 16 + ll;
      const int k0i = kb + lg * 4;
      float p0 = (k0i + 0 <= qrow) ? s[0] * (RSQ * __expf(a4[0] - Mq[qg])) : 0.f;
      float p1 = (k0i + 1 <= qrow) ? s[1] * (RSQ * __expf(a4[1] - Mq[qg])) : 0.f;
      float p2 = (k0i + 2 <= qrow) ? s[2] * (RSQ * __expf(a4[2] - Mq[qg])) : 0.f;
      float p3 = (k0i + 3 <= qrow) ? s[3] * (RSQ * __expf(a4[3] - Mq[qg])) : 0.f;
      rsum[qg] += (p0 + p1) + (p2 + p3);
      uint2 pk = make_uint2(pk2bf(p0, p1), pk2bf(p2, p3));
      *(uint2*)&Pls[tj & 1][(qg * 16 + ll) * PSTR + w * 16 + lg * 4] = pk;
    }
    __syncthreads();
    // ---- PV: V frags from L2, P frags from LDS, 16 MFMA ----
    const unsigned short* vp = Vt + ((size_t)bh * DHx + w * 32 + ll) * Sx + j0 + lg * 8;
#pragma unroll
    for (int kap = 0; kap < 4; ++kap) {
      bf16x8 pf0 = *(const bf16x8*)&Pls[tj & 1][ll * PSTR + kap * 32 + lg * 8];
      bf16x8 pf1 = *(const bf16x8*)&Pls[tj & 1][(16 + ll) * PSTR + kap * 32 + lg * 8];
#pragma unroll
      for (int dt = 0; dt < 2; ++dt) {
        bf16x8 vf = *(const bf16x8*)(vp + (size_t)dt * 16 * Sx + kap * 32);
        acc[dt][0] = __builtin_amdgcn_mfma_f32_16x16x32_bf16(vf, pf0, acc[dt][0], 0, 0, 0);
        acc[dt][1] = __builtin_amdgcn_mfma_f32_16x16x32_bf16(vf, pf1, acc[dt][1], 0, 0, 0);
      }
    }
  }

  // ---- cross-wave reductions: rsum (QK role), s1/s2 (PV role) ----
#pragma unroll
  for (int qg = 0; qg < 2; ++qg) {
    float rs = rsum[qg];
    float s1 = 0.f, s2 = 0.f;
#pragma unroll
    for (int dt = 0; dt < 2; ++dt)
#pragma unroll
      for (int r = 0; r < 4; ++r) {
        const float x = acc[dt][qg][r];
        s1 += x; s2 += x * x;
      }
    rs += __shfl_xor(rs, 16); rs += __shfl_xor(rs, 32);
    s1 += __shfl_xor(s1, 16); s1 += __shfl_xor(s1, 32);
    s2 += __shfl_xor(s2, 16); s2 += __shfl_xor(s2, 32);
    if (l < 16) {
      red[w][qg][l][0] = rs;
      red[w][qg][l][1] = s1;
      red[w][qg][l][2] = s2;
    }
  }
  __syncthreads();

  // ---- epilogue: normalizer + group-LN, direct from accumulators ----
#pragma unroll
  for (int qg = 0; qg < 2; ++qg) {
    const int q = qg * 16 + ll;
    float rs = 0.f, s1 = 0.f, s2 = 0.f;
#pragma unroll
    for (int wj = 0; wj < 8; ++wj) {
      rs += red[wj][qg][ll][0];
      s1 += red[wj][qg][ll][1];
      s2 += red[wj][qg][ll][2];
    }
    const float inv = 1.f / (fmaxf(fabsf(rs), nfq[qg]) + 1e-6f);
    const float mean = s1 * inv * (1.f / 256.f);
    const float ex2  = s2 * inv * inv * (1.f / 256.f);
    const float var  = ex2 - mean * mean;
    const float rstd = rsqrtf(var + 1e-5f);
    float* op = out + ((size_t)b * Sx + i0 + q) * Hx + h * DHx;
#pragma unroll
    for (int dt = 0; dt < 2; ++dt) {
      const int dbase = w * 32 + dt * 16 + lg * 4;
      f32x4 lw = *(const f32x4*)(lnw + h * DHx + dbase);
      float4 o;
      o.x = (acc[dt][qg][0] * inv - mean) * rstd * (1.f + lw[0]);
      o.y = (acc[dt][qg][1] * inv - mean) * rstd * (1.f + lw[1]);
      o.z = (acc[dt][qg][2] * inv - mean) * rstd * (1.f + lw[2]);
      o.w = (acc[dt][qg][3] * inv - mean) * rstd * (1.f + lw[3]);
      *(float4*)(op + dbase) = o;
    }
  }
}

extern "C" void kernel_launch(void* const* d_in, const int* in_sizes, int n_in,
                              void* d_out, int out_size, void* d_ws, size_t ws_size,
                              hipStream_t stream) {
  const float* q   = (const float*)d_in[0];
  const float* k   = (const float*)d_in[1];
  const float* v   = (const float*)d_in[2];
  const float* wi  = (const float*)d_in[3];
  const float* bi  = (const float*)d_in[4];
  const float* wf  = (const float*)d_in[5];
  const float* bf  = (const float*)d_in[6];
  const float* lnw = (const float*)d_in[7];
  float* out = (float*)d_out;
  float* ws  = (float*)d_ws;

  const int G = Bx * NHx * Sx;         // 16384
  float* ig  = ws;
  float* fg  = ws + (size_t)G;
  float* av  = ws + (size_t)2 * G;
  float* Mv  = ws + (size_t)3 * G;
  float* nfv = ws + (size_t)4 * G;
  unsigned short* Qb = (unsigned short*)(ws + (size_t)5 * G);
  unsigned short* Kb = Qb + (size_t)Bx * Sx * Hx;   // 4,194,304 elems
  unsigned short* Vt = Kb + (size_t)Bx * Sx * Hx;
  // total ws use: ~24.3 MB

  gates_kernel<<<Bx * Sx, 256, 0, stream>>>(q, k, v, wi, bi, wf, bf, ig, fg, Qb, Kb);
  scan_kernel<<<Bx * NHx, 256, 0, stream>>>(ig, fg, av, Mv, nfv);
  dim3 gT(Sx / 64, DHx / 64, Bx * NHx);
  vtrans_kernel<<<gT, 256, 0, stream>>>(v, Vt);
  dim3 g4(Bx * NHx, Sx / 32);          // x = bh (XCD affinity), y = q-tile
  mlstm_mfma<<<g4, 512, 0, stream>>>(Qb, Kb, Vt, av, Mv, nfv, lnw, out);
}